// Round 7
// baseline (3866.960 us; speedup 1.0000x reference)
//
#include <hip/hip_runtime.h>
#include <math.h>
#include <stdint.h>

#define NTAGS 512
#define SEQL  512
#define BATCH 64
#define START_TAG 510
#define STOP_TAG  511
#define NEG_INF  -10000.0f

#define NB   64                 // blocks; block b owns rows [8b, 8b+8) and batch b
#define BT   512                // 8 waves; wave w owns row 8*bid + w
#define ROWS 8

// ws layout (bytes)
#define WS_NUM_OFF  0                     // float numerator accumulator
#define WS_SLOT_OFF 256                   // uint64 slots [2][NTAGS]: (tag<<32)|f32bits
#define WS_BYTES    (WS_SLOT_OFF + 2 * NTAGS * 8)

#define AGLD(p) __hip_atomic_load((p), __ATOMIC_RELAXED, __HIP_MEMORY_SCOPE_AGENT)

__global__ __launch_bounds__(BT) void crf_fused(
    const float* __restrict__ inputs, const int* __restrict__ tags,
    const float* __restrict__ trans, void* __restrict__ ws,
    float* __restrict__ out)
{
    const int tid   = threadIdx.x;
    const int bid   = blockIdx.x;
    const int lane  = tid & 63;
    const int wave  = tid >> 6;
    const int myrow = bid * ROWS + wave;

    float*    numacc = (float*)((char*)ws + WS_NUM_OFF);
    uint64_t* slots  = (uint64_t*)((char*)ws + WS_SLOT_OFF);

    // ---- my transition row lives in REGISTERS: treg[q] = T[myrow][lane+64q] ----
    float treg[8];
    {
        const float* trow = trans + (size_t)myrow * NTAGS;
        #pragma unroll
        for (int q = 0; q < 8; ++q) treg[q] = trow[lane + 64 * q];   // coalesced 256B/wave
    }

    // ---- numerator: block b == batch b, thread t == position t ----
    float ns;
    {
        const int*   tg  = tags + bid * SEQL;
        const float* inb = inputs + (size_t)bid * SEQL * NTAGS;
        if (tid > 0) {
            const int cur = tg[tid], prev = tg[tid - 1];
            ns = trans[cur * NTAGS + prev] + inb[(size_t)(tid - 1) * NTAGS + cur];
        } else {
            ns = trans[tg[0] * NTAGS + START_TAG] + trans[STOP_TAG * NTAGS + tg[SEQL - 1]];
        }
    }
    #pragma unroll
    for (int off = 32; off; off >>= 1) ns += __shfl_xor(ns, off);
    if (lane == 0) atomicAdd(numacc, ns);
    __builtin_amdgcn_s_waitcnt(0);   // RMW retired at coherence point before any publish

    // ---- analytic step-0 partials: v = fv0 + T[myrow]; shift = analytic prev max ----
    // (START row: T[START][*] = -1e4 so v - shift in {0, -1e4} -> exp in {1, 0}; no overflow)
    float shift = (myrow == START_TAG) ? NEG_INF : 0.0f;
    float mP = -3.4e38f, ssP = 0.0f;
    #pragma unroll
    for (int q = 0; q < 8; ++q) {
        const float f0 = (lane + 64 * q == START_TAG) ? 0.0f : NEG_INF;
        const float v  = f0 + treg[q];
        mP  = fmaxf(mP, v);
        ssP += __expf(v - shift);
    }

    float f[8];   // fv chunk values (used by terminal after the loop)

    // =================== 512 serial steps, zero barriers ===================
    for (int k = 1; k <= SEQL; ++k) {
        uint64_t* buf = slots + (unsigned)(k & 1) * NTAGS;
        const unsigned want = (unsigned)k;

        // early probes (depth-1): in flight across butterfly + publish
        uint64_t pv0[8];
        #pragma unroll
        for (int q = 0; q < 8; ++q) pv0[q] = AGLD(&buf[(q << 6) + lane]);

        // reduce my partials: two independent butterflies, single 6-stage latency
        float m = mP, ss = ssP;
        #pragma unroll
        for (int off = 32; off; off >>= 1) {
            const float m2 = __shfl_xor(m, off);
            const float s2 = __shfl_xor(ss, off);
            m  = fmaxf(m, m2);
            ss += s2;
        }

        // fv_k[myrow] = lse(v) - max(v) = log(ss) + shift - m ; publish tagged atom
        {
            const float nv = __logf(ss) + shift - m;
            if (lane == 0) {
                const uint64_t pk = ((uint64_t)want << 32) | (uint64_t)__float_as_uint(nv);
                __hip_atomic_store(&buf[myrow], pk, __ATOMIC_RELAXED, __HIP_MEMORY_SCOPE_AGENT);
            }
        }
        shift = m;                    // wave-uniform: next step's sum shift
        mP = -3.4e38f; ssP = 0.0f;    // restart partials; accumulate on arrival below

        // second probe per slot -> depth-2 rotation (probe period ~ RTT/2)
        uint64_t pv1[8];
        #pragma unroll
        for (int q = 0; q < 8; ++q) pv1[q] = AGLD(&buf[(q << 6) + lane]);

        // ---- sweep: per-lane pending mask; accumulate each chunk as it arrives.
        // Critical path = last arrival + 1 exp + butterfly (next iter), nothing else.
        unsigned pend = 0xFFu;
        while (__ballot(pend != 0)) {
            #pragma unroll
            for (int q = 0; q < 8; ++q) {
                if (pend & (1u << q)) {
                    if ((unsigned)(pv0[q] >> 32) == want) {
                        const float fq = __uint_as_float((unsigned)(pv0[q] & 0xFFFFFFFFu));
                        f[q] = fq;
                        const float v = fq + treg[q];
                        mP  = fmaxf(mP, v);
                        ssP += __expf(v - shift);
                        pend &= ~(1u << q);
                    } else {
                        pv0[q] = pv1[q];
                        pv1[q] = AGLD(&buf[(q << 6) + lane]);
                    }
                }
            }
        }
    }

    // ---- terminal by the wave owning row STOP (block 63, wave 7): treg == T[STOP] ----
    if (myrow == STOP_TAG) {
        float v[8];
        #pragma unroll
        for (int q = 0; q < 8; ++q) v[q] = f[q] + treg[q];   // f[] holds fv_512
        float m = fmaxf(fmaxf(fmaxf(v[0], v[1]), fmaxf(v[2], v[3])),
                        fmaxf(fmaxf(v[4], v[5]), fmaxf(v[6], v[7])));
        // safe unshifted sum: real terms bounded by e^~11
        float ss = ((__expf(v[0]) + __expf(v[1])) + (__expf(v[2]) + __expf(v[3])))
                 + ((__expf(v[4]) + __expf(v[5])) + (__expf(v[6]) + __expf(v[7])));
        #pragma unroll
        for (int off = 32; off; off >>= 1) {
            const float ms  = __shfl_xor(m, off);
            const float sss = __shfl_xor(ss, off);
            m  = fmaxf(m, ms);
            ss += sss;
        }
        if (lane == 0) {
            const float ld  = __logf(ss) - m;       // log_denominator
            // all tag-512 publishes observed => all numerator RMWs (program-order
            // earlier, drained by s_waitcnt) are retired at the coherence point.
            const float num = AGLD(numacc);
            out[0] = num - (float)BATCH * ld;
        }
    }
}

extern "C" void kernel_launch(void* const* d_in, const int* in_sizes, int n_in,
                              void* d_out, int out_size, void* d_ws, size_t ws_size,
                              hipStream_t stream)
{
    const float* inputs = (const float*)d_in[0];   // (64, 512, 512) fp32
    const int*   tags   = (const int*)  d_in[1];   // (64, 512) int32
    const float* trans  = (const float*)d_in[2];   // (512, 512) fp32
    float* out = (float*)d_out;

    // zero numerator accumulator + tag slots (valid tags are 1..512)
    hipMemsetAsync(d_ws, 0, WS_BYTES, stream);

    crf_fused<<<NB, BT, 0, stream>>>(inputs, tags, trans, d_ws, out);
}

// Round 8
// 833.406 us; speedup vs baseline: 4.6399x; 4.6399x over previous
//
#include <hip/hip_runtime.h>
#include <math.h>
#include <stdint.h>

#define NTAGS 512
#define SEQL  512
#define BATCH 64
#define START_TAG 510
#define STOP_TAG  511
#define NEG_INF  -10000.0f

#define NB   64                 // blocks; block b owns rows [8b, 8b+8) and batch b
#define BT   512                // 8 waves; wave w owns row 8*bid + w
#define ROWS 8
#define REPS 8                  // slot-buffer replicas; block polls replica bid&7

// ws layout (bytes)
#define WS_NUM_OFF  0                     // float numerator accumulator
#define WS_SLOT_OFF 256                   // uint64 slots [2][REPS][NTAGS]: (tag<<32)|f32bits
#define WS_BYTES    (WS_SLOT_OFF + 2 * REPS * NTAGS * 8)

#define AGLD(p) __hip_atomic_load((p), __ATOMIC_RELAXED, __HIP_MEMORY_SCOPE_AGENT)

__global__ __launch_bounds__(BT) void crf_fused(
    const float* __restrict__ inputs, const int* __restrict__ tags,
    const float* __restrict__ trans, void* __restrict__ ws,
    float* __restrict__ out)
{
    __shared__ float fv_lds[2][NTAGS];      // 4 KB ping-pong forward variable

    const int tid   = threadIdx.x;
    const int bid   = blockIdx.x;
    const int lane  = tid & 63;
    const int wave  = tid >> 6;
    const int myrow = bid * ROWS + wave;
    const int rep   = bid & (REPS - 1);

    float*    numacc = (float*)((char*)ws + WS_NUM_OFF);
    uint64_t* slots  = (uint64_t*)((char*)ws + WS_SLOT_OFF);

    // ---- my transition row in REGISTERS: treg[q] = T[myrow][lane+64q] ----
    float treg[8];
    {
        const float* trow = trans + (size_t)myrow * NTAGS;
        #pragma unroll
        for (int q = 0; q < 8; ++q) treg[q] = trow[lane + 64 * q];   // coalesced 256B/wave
    }

    // ---- numerator: block b == batch b, thread t == position t ----
    float ns;
    {
        const int*   tg  = tags + bid * SEQL;
        const float* inb = inputs + (size_t)bid * SEQL * NTAGS;
        if (tid > 0) {
            const int cur = tg[tid], prev = tg[tid - 1];
            ns = trans[cur * NTAGS + prev] + inb[(size_t)(tid - 1) * NTAGS + cur];
        } else {
            ns = trans[tg[0] * NTAGS + START_TAG] + trans[STOP_TAG * NTAGS + tg[SEQL - 1]];
        }
    }
    #pragma unroll
    for (int off = 32; off; off >>= 1) ns += __shfl_xor(ns, off);
    if (lane == 0) atomicAdd(numacc, ns);
    __builtin_amdgcn_s_waitcnt(0);   // RMW retired at coherence point before any publish

    // init fv0 in LDS ping buffer 0
    fv_lds[0][tid] = (tid == START_TAG) ? 0.0f : NEG_INF;
    __syncthreads();

    // sum-shift = previous step's row max (step-0 value known analytically)
    float mprev = (myrow == START_TAG) ? NEG_INF : 0.0f;

    for (int s = 0; s < SEQL; ++s) {
        const int pp = (s + 1) & 1;
        uint64_t* pubbase = slots + (size_t)pp * REPS * NTAGS;          // + lane*NTAGS + myrow
        uint64_t* myslot  = slots + ((size_t)pp * REPS + rep) * NTAGS + tid;
        const unsigned want = (unsigned)(s + 1);
        const float* fvc = fv_lds[s & 1];

        // early probe: overlaps compute + publish (others' s+1 may already arrive)
        uint64_t p = AGLD(myslot);

        // ---- my row: v = fv + T[row]; m = max(v); ss = sum exp(v - mprev) ----
        float v[8];
        #pragma unroll
        for (int q = 0; q < 8; ++q)                 // 2-way LDS alias only (free)
            v[q] = fvc[lane + 64 * q] + treg[q];

        float m = fmaxf(fmaxf(fmaxf(v[0], v[1]), fmaxf(v[2], v[3])),
                        fmaxf(fmaxf(v[4], v[5]), fmaxf(v[6], v[7])));
        float ss = ((__expf(v[0] - mprev) + __expf(v[1] - mprev))
                  + (__expf(v[2] - mprev) + __expf(v[3] - mprev)))
                 + ((__expf(v[4] - mprev) + __expf(v[5] - mprev))
                  + (__expf(v[6] - mprev) + __expf(v[7] - mprev)));

        // two INDEPENDENT butterflies, interleaved -> single 6-stage latency
        #pragma unroll
        for (int off = 32; off; off >>= 1) {
            const float ms  = __shfl_xor(m, off);
            const float sss = __shfl_xor(ss, off);
            m  = fmaxf(m, ms);
            ss += sss;
        }

        // fv'[row] = log(ss) + mprev - m  (uniform across lanes after butterfly);
        // lanes 0-7 publish the tagged atom to all 8 replicas in ONE instruction.
        {
            const float nv = __logf(ss) + mprev - m;
            const uint64_t pk = ((uint64_t)want << 32) | (uint64_t)__float_as_uint(nv);
            if (lane < REPS)
                __hip_atomic_store(pubbase + (size_t)lane * NTAGS + myrow, pk,
                                   __ATOMIC_RELAXED, __HIP_MEMORY_SCOPE_AGENT);
        }
        mprev = m;

        // ---- pipelined poll of MY single slot (replica bid&7): 4 loads in flight ----
        if ((unsigned)(p >> 32) != want) {
            uint64_t q0 = AGLD(myslot), q1 = AGLD(myslot),
                     q2 = AGLD(myslot), q3 = AGLD(myslot);
            for (;;) {
                if ((unsigned)(q0 >> 32) == want) { p = q0; break; }
                q0 = AGLD(myslot);
                if ((unsigned)(q1 >> 32) == want) { p = q1; break; }
                q1 = AGLD(myslot);
                if ((unsigned)(q2 >> 32) == want) { p = q2; break; }
                q2 = AGLD(myslot);
                if ((unsigned)(q3 >> 32) == want) { p = q3; break; }
                q3 = AGLD(myslot);
            }
        }
        fv_lds[pp][tid] = __uint_as_float((unsigned)(p & 0xFFFFFFFFu));
        __syncthreads();   // depth-2 ping-pong: one sync per step suffices
    }

    // ---- terminal by the wave that owns row STOP (block 63, wave 7) ----
    if (myrow == STOP_TAG) {
        const float* fvf = fv_lds[0];               // tag 512 lives in buffer 0
        float v[8];
        #pragma unroll
        for (int q = 0; q < 8; ++q)
            v[q] = fvf[lane + 64 * q] + treg[q];    // treg == T[STOP][*]
        float m = fmaxf(fmaxf(fmaxf(v[0], v[1]), fmaxf(v[2], v[3])),
                        fmaxf(fmaxf(v[4], v[5]), fmaxf(v[6], v[7])));
        // safe unshifted sum: real terms bounded by e^~11
        float ss = ((__expf(v[0]) + __expf(v[1])) + (__expf(v[2]) + __expf(v[3])))
                 + ((__expf(v[4]) + __expf(v[5])) + (__expf(v[6]) + __expf(v[7])));
        #pragma unroll
        for (int off = 32; off; off >>= 1) {
            const float ms  = __shfl_xor(m, off);
            const float sss = __shfl_xor(ss, off);
            m  = fmaxf(m, ms);
            ss += sss;
        }
        if (lane == 0) {
            const float ld  = __logf(ss) - m;       // log_denominator
            const float num = AGLD(numacc);
            out[0] = num - (float)BATCH * ld;
        }
    }
}

extern "C" void kernel_launch(void* const* d_in, const int* in_sizes, int n_in,
                              void* d_out, int out_size, void* d_ws, size_t ws_size,
                              hipStream_t stream)
{
    const float* inputs = (const float*)d_in[0];   // (64, 512, 512) fp32
    const int*   tags   = (const int*)  d_in[1];   // (64, 512) int32
    const float* trans  = (const float*)d_in[2];   // (512, 512) fp32
    float* out = (float*)d_out;

    // zero numerator accumulator + tag slots (valid tags are 1..512)
    hipMemsetAsync(d_ws, 0, WS_BYTES, stream);

    crf_fused<<<NB, BT, 0, stream>>>(inputs, tags, trans, d_ws, out);
}